// Round 11
// baseline (234.447 us; speedup 1.0000x reference)
//
#include <hip/hip_runtime.h>
#include <math.h>

#define NATOMS 10000
#define NEDGES 320000
#define CAP    64             // fixed record capacity per (atom,species) bin
#define RC_F 5.0f
#define PI_F 3.14159265358979323846f

// radial table: T[k][0..47] = (R * fc)(d_k), d_k = k * RC/(NK-1), linear interp
#define NK   16384
#define TROW 48
#define HINV_F ((float)(NK - 1) / RC_F)

// ---- workspace layout (in floats) ----
#define WS_SEMB   0         // 12 floats
#define WS_CNT    16        // NATOMS int4 (species counts 0..2, .w unused)
#define WS_SD     440096    // NATOMS*3*CAP float4 records (30.7 MB), fixed-cap bins
#define WS_TAB    8200096   // NK*TROW floats (3 MB) radial table
#define WS_WA1T   9000000   // 64 x 192 transposed Wa1
#define WS_WA2T   9012288   // 64 x 64  transposed Wa2
#define WS_FEAT   9016384   // NATOMS x 192 per-atom features

// multinomial term tables (global component index 0..34)
__device__ __constant__ int   d_PWA[35] = {0, 0,0,1, 0,0,0,1,1,2, 0,0,0,0,1,1,1,2,2,3, 0,0,0,0,0,1,1,1,1,2,2,2,3,3,4};
__device__ __constant__ int   d_PWB[35] = {0, 0,1,0, 0,1,2,0,1,0, 0,1,2,3,0,1,2,0,1,0, 0,1,2,3,4,0,1,2,3,0,1,2,0,1,0};
__device__ __constant__ int   d_PWC[35] = {0, 1,0,0, 2,1,0,1,0,0, 3,2,1,0,2,1,0,1,0,0, 4,3,2,1,0,3,2,1,0,2,1,0,1,0,0};
__device__ __constant__ float d_NM[35]  = {1.f, 1.f,1.f,1.f, 1.f,2.f,1.f,2.f,2.f,1.f,
                                           1.f,3.f,3.f,1.f,3.f,6.f,3.f,3.f,3.f,1.f,
                                           1.f,4.f,6.f,4.f,1.f,4.f,12.f,12.f,4.f,6.f,12.f,6.f,4.f,4.f,1.f};
__device__ __constant__ int   d_LBLK[35]= {0, 1,1,1, 2,2,2,2,2,2, 3,3,3,3,3,3,3,3,3,3, 4,4,4,4,4,4,4,4,4,4,4,4,4,4,4};
__device__ __constant__ int   d_L6[6]   = {0,1,4,10,20,35};

__device__ __forceinline__ float siluf(float x) { return x / (1.0f + __expf(-x)); }

__device__ __forceinline__ float2 f2fma(float2 a, float2 b, float2 c) {
  return make_float2(fmaf(a.x, b.x, c.x), fmaf(a.y, b.y, c.y));
}

__device__ __forceinline__ float psel(float x, int p) {
  float x2 = x * x;
  float r = 1.0f;
  r = (p == 1) ? x : r;
  r = (p == 2) ? x2 : r;
  r = (p == 3) ? x2 * x : r;
  r = (p == 4) ? x2 * x2 : r;
  return r;
}

// ---------------- k_pre: zero counters + species embedding + radial table + W transposes ----------------
__global__ __launch_bounds__(256) void k_pre(
    const float* __restrict__ Wr1, const float* __restrict__ br1,
    const float* __restrict__ Wr2, const float* __restrict__ br2,
    const float* __restrict__ Ws1, const float* __restrict__ bs1,
    const float* __restrict__ Ws2, const float* __restrict__ bs2,
    const float* __restrict__ Wa1, const float* __restrict__ Wa2,
    float* __restrict__ ws)
{
  int gt = blockIdx.x * 256 + threadIdx.x;

  if (gt < NATOMS) ((int4*)(ws + WS_CNT))[gt] = make_int4(0, 0, 0, 0);
  if (gt < 12) {
    int t = gt >> 2, s = gt & 3;
    float acc = bs2[s];
    for (int j = 0; j < 16; j++) acc += tanhf(Ws1[t * 16 + j] + bs1[j]) * Ws2[j * 4 + s];
    ws[WS_SEMB + gt] = acc;
  }
  // weight transposes: Wa1T[c][k] = Wa1[k][c], Wa2T[c][k] = Wa2[k][c]
  if (gt < 64 * 192) {
    int c = gt / 192, k = gt % 192;
    ws[WS_WA1T + gt] = Wa1[k * 64 + c];
  }
  if (gt >= 64 * 192 && gt < 64 * 192 + 64 * 64) {
    int g2 = gt - 64 * 192;
    int c = g2 / 64, k = g2 % 64;
    ws[WS_WA2T + g2] = Wa2[k * 64 + c];
  }

  // radial table: item = (knot k, slice sl)
  int sl = gt % 12;
  int k  = gt / 12;           // 0..NK-1 exactly
  float dk = (float)k * (RC_F / (float)(NK - 1));
  float d = fmaxf(dk, 1e-6f);
  float invd = 1.0f / d;
  float theta = (PI_F / RC_F) * d;
  float s1 = sinf(theta), c1 = cosf(theta);
  float fc = (d < RC_F) ? 0.5f * (c1 + 1.0f) : 0.0f;
  float bes[8];
  {
    float sq = sqrtf(2.0f / RC_F) * invd;
    float twoc = 2.0f * c1;
    float sp = 0.0f, sc = s1;
    #pragma unroll
    for (int q = 0; q < 8; q++) {
      bes[q] = sq * sc;
      float sn = twoc * sc - sp;
      sp = sc; sc = sn;
    }
  }
  float h1[64];
  #pragma unroll
  for (int j4 = 0; j4 < 16; j4++) {
    float2 a01 = *(const float2*)&br1[j4 * 4];
    float2 a23 = *(const float2*)&br1[j4 * 4 + 2];
    #pragma unroll
    for (int q = 0; q < 8; q++) {
      float2 b2 = make_float2(bes[q], bes[q]);
      a01 = f2fma(b2, *(const float2*)&Wr1[q * 64 + j4 * 4],     a01);
      a23 = f2fma(b2, *(const float2*)&Wr1[q * 64 + j4 * 4 + 2], a23);
    }
    h1[j4 * 4 + 0] = siluf(a01.x);
    h1[j4 * 4 + 1] = siluf(a01.y);
    h1[j4 * 4 + 2] = siluf(a23.x);
    h1[j4 * 4 + 3] = siluf(a23.y);
  }
  int j0 = sl * 4;
  float2 a01 = *(const float2*)&br2[j0];
  float2 a23 = *(const float2*)&br2[j0 + 2];
  for (int q = 0; q < 64; q++) {
    float2 h2 = make_float2(h1[q], h1[q]);
    a01 = f2fma(h2, *(const float2*)&Wr2[q * 48 + j0],     a01);
    a23 = f2fma(h2, *(const float2*)&Wr2[q * 48 + j0 + 2], a23);
  }
  *(float4*)(ws + WS_TAB + (size_t)k * TROW + j0) =
      make_float4(siluf(a01.x) * fc, siluf(a01.y) * fc,
                  siluf(a23.x) * fc, siluf(a23.y) * fc);
}

// ---------------- k_scatter: direct allocation into fixed-capacity bins ----------------
__global__ __launch_bounds__(256) void k_scatter(
    const float* __restrict__ rij,
    const int* __restrict__ first_atom, const int* __restrict__ second_atom,
    const int* __restrict__ species, float* __restrict__ ws)
{
  int e = blockIdx.x * 256 + threadIdx.x;   // grid exact: NEDGES = 1250*256
  int* cnt = (int*)(ws + WS_CNT);
  int a = first_atom[e];
  int t = species[second_atom[e]];
  int pos = atomicAdd(&cnt[a * 4 + t], 1);
  float x = rij[e * 3 + 0], y = rij[e * 3 + 1], z = rij[e * 3 + 2];
  float d = sqrtf(x * x + y * y + z * z + 1e-12f);
  float invd = 1.0f / d;
  if (pos < CAP)
    ((float4*)(ws + WS_SD))[(size_t)a * (3 * CAP) + t * CAP + pos] =
        make_float4(x * invd, y * invd, z * invd, d);
}

// ---------------- k_acc: round-7 edge phase + fout -> feat (no MLP tail) ----------------
__global__ __launch_bounds__(128) void k_acc(float* __restrict__ ws)
{
  __shared__ __align__(16) float sScr[2][864];
  int tid = threadIdx.x;
  int lane = tid & 63, wv = tid >> 6;
  int a = blockIdx.x * 2 + wv;          // NATOMS = 5000*2 exact
  float* sStage = &sScr[wv][0];         // 16 records x 52 floats (during runs)
  float* sG     = &sScr[wv][0];         // 24 x 36 (after runs; overlays sStage)

  const float4* sd4 = (const float4*)(ws + WS_SD);
  const float* tab = ws + WS_TAB;

  const int c = lane;
  bool isc = (c < 35);
  int pa = 0, pb = 0, pcw = 0, lb = 0;
  if (isc) { pa = d_PWA[c]; pb = d_PWB[c]; pcw = d_PWC[c]; lb = d_LBLK[c]; }
  int rdir = lane - 35;
  bool isd = (rdir >= 0) && (rdir < 8);
  int rl = lane >> 4, fl = lane & 15;
  int s = lane & 3;
  float se0 = ws[WS_SEMB + s], se1 = ws[WS_SEMB + 4 + s], se2 = ws[WS_SEMB + 8 + s];

  int4 cv = ((const int4*)(ws + WS_CNT))[a];
  int c0n = cv.x > CAP ? CAP : cv.x;
  int c1n = cv.y > CAP ? CAP : cv.y;
  int c2n = cv.z > CAP ? CAP : cv.z;

  float2 g2[3][4];
  #pragma unroll
  for (int t2 = 0; t2 < 3; t2++)
    #pragma unroll
    for (int r = 0; r < 4; r++) g2[t2][r] = make_float2(0.f, 0.f);
  float g0[3] = {0.0f, 0.0f, 0.0f};

#define CORE(T) {                                                             \
    const float* rb = sStage + j * 52;                                        \
    if (isc) {                                                                \
      float4 rh = *(const float4*)(rb + 48);                                  \
      float comp = psel(rh.x, pa) * psel(rh.y, pb) * psel(rh.z, pcw);         \
      float2 c2v = make_float2(comp, comp);                                   \
      const float2* r2 = (const float2*)(rb + 8 + 8 * lb);                    \
      g2[T][0] = f2fma(c2v, r2[0], g2[T][0]);                                 \
      g2[T][1] = f2fma(c2v, r2[1], g2[T][1]);                                 \
      g2[T][2] = f2fma(c2v, r2[2], g2[T][2]);                                 \
      g2[T][3] = f2fma(c2v, r2[3], g2[T][3]);                                 \
    } else if (isd) {                                                         \
      g0[T] += rb[rdir];                                                      \
    }                                                                         \
  }

#define RUNT(T, CT) {                                                         \
    const float4* rbase = sd4 + (size_t)a * (3 * CAP) + (T) * CAP;            \
    for (int cb = 0; cb < (CT); cb += 16) {                                   \
      int m = (CT) - cb; if (m > 16) m = 16;                                  \
      float4 ed = rbase[cb + ((lane < m) ? lane : (m - 1))];                  \
      float fi = ed.w * HINV_F;                                               \
      int ii = (int)fi;                                                       \
      ii = (ii > NK - 2) ? (NK - 2) : ii;                                     \
      float w = fi - (float)ii;                                               \
      int rowb = ii * TROW;                                                   \
      int R = (m + 3) >> 2;                                                   \
      for (int r = 0; r < R; r++) {                                           \
        int sl = r * 4 + rl;                                                  \
        float w_s = __shfl(w, sl, 64);                                        \
        int   rb_ = __shfl(rowb, sl, 64);                                     \
        float sx = __shfl(ed.x, sl, 64), sy = __shfl(ed.y, sl, 64);           \
        float sz = __shfl(ed.z, sl, 64);                                      \
        if (fl < 12) {                                                        \
          const float* tp = tab + rb_ + fl * 4;                               \
          float4 t0 = *(const float4*)(tp);                                   \
          float4 t1 = *(const float4*)(tp + TROW);                            \
          float4 v;                                                           \
          v.x = fmaf(w_s, t1.x - t0.x, t0.x);                                 \
          v.y = fmaf(w_s, t1.y - t0.y, t0.y);                                 \
          v.z = fmaf(w_s, t1.z - t0.z, t0.z);                                 \
          v.w = fmaf(w_s, t1.w - t0.w, t0.w);                                 \
          *(float4*)(sStage + sl * 52 + fl * 4) = v;                          \
        } else if (fl == 12) {                                                \
          *(float4*)(sStage + sl * 52 + 48) = make_float4(sx, sy, sz, 0.0f);  \
        }                                                                     \
      }                                                                       \
      for (int j = 0; j < m; j++) CORE(T)                                     \
    }                                                                         \
  }

  RUNT(0, c0n)
  RUNT(1, c1n)
  RUNT(2, c2n)
#undef RUNT
#undef CORE

  if (isc) {
    #pragma unroll
    for (int t2 = 0; t2 < 3; t2++)
      #pragma unroll
      for (int r = 0; r < 8; r++) {
        float gval = (r & 1) ? g2[t2][r >> 1].y : g2[t2][r >> 1].x;
        sG[(t2 * 8 + r) * 36 + c] = gval;
      }
  } else if (isd) {
    #pragma unroll
    for (int t2 = 0; t2 < 3; t2++) sG[(t2 * 8 + rdir) * 36 + 35] = g0[t2];
  }

  float* featr = ws + WS_FEAT + (size_t)a * 192;
  #pragma unroll
  for (int u = 0; u < 3; u++) {
    int f = lane + 64 * u;
    int blk = f >> 5, rr = (f >> 2) & 7;
    float acc;
    if (blk == 0) {
      acc = se0 * sG[(0 + rr) * 36 + 35] + se1 * sG[(8 + rr) * 36 + 35] + se2 * sG[(16 + rr) * 36 + 35];
    } else {
      int cc0 = d_L6[blk - 1], cc1 = d_L6[blk];
      acc = 0.0f;
      for (int cc = cc0; cc < cc1; cc++) {
        float A = se0 * sG[(0 + rr) * 36 + cc] + se1 * sG[(8 + rr) * 36 + cc] + se2 * sG[(16 + rr) * 36 + cc];
        acc += d_NM[cc] * A * A;
      }
    }
    featr[f] = acc;
  }
}

// ---------------- k_mlp: per-atom MLP with transposed-weight vector loads ----------------
// block 256 = 4 waves, one atom per wave; feat broadcast via LDS scratch.
__global__ __launch_bounds__(256) void k_mlp(
    const float* __restrict__ ws,
    const float* __restrict__ ba1, const float* __restrict__ ba2,
    const float* __restrict__ Wa3, const float* __restrict__ ba3,
    float* __restrict__ out)
{
  __shared__ __align__(16) float sF[4][192];
  int lane = threadIdx.x & 63, wv = threadIdx.x >> 6;
  int a = blockIdx.x * 4 + wv;          // 2500*4 = 10000 exact

  const float* fr = ws + WS_FEAT + (size_t)a * 192;
  float f0 = fr[lane], f1 = fr[lane + 64], f2 = fr[lane + 128];
  sF[wv][lane] = f0; sF[wv][lane + 64] = f1; sF[wv][lane + 128] = f2;

  const float* w1 = ws + WS_WA1T + (size_t)lane * 192;
  float a0 = 0.f, a1 = 0.f, a2 = 0.f, a3 = 0.f;
  #pragma unroll
  for (int k4 = 0; k4 < 48; k4++) {
    float4 f4 = *(const float4*)(&sF[wv][k4 * 4]);
    float4 w4 = *(const float4*)(w1 + k4 * 4);
    a0 += f4.x * w4.x;
    a1 += f4.y * w4.y;
    a2 += f4.z * w4.z;
    a3 += f4.w * w4.w;
  }
  float h = siluf(a0 + a1 + a2 + a3 + ba1[lane]);

  sF[wv][lane] = h;   // wave-lockstep: all Wa1 reads complete before this store
  const float* w2 = ws + WS_WA2T + (size_t)lane * 64;
  float b0 = 0.f, b1 = 0.f, b2 = 0.f, b3 = 0.f;
  #pragma unroll
  for (int k4 = 0; k4 < 16; k4++) {
    float4 h4 = *(const float4*)(&sF[wv][k4 * 4]);
    float4 w4 = *(const float4*)(w2 + k4 * 4);
    b0 += h4.x * w4.x;
    b1 += h4.y * w4.y;
    b2 += h4.z * w4.z;
    b3 += h4.w * w4.w;
  }
  float h2 = siluf(b0 + b1 + b2 + b3 + ba2[lane]);
  float pr = h2 * Wa3[lane];
  #pragma unroll
  for (int off = 32; off > 0; off >>= 1) pr += __shfl_down(pr, off, 64);
  if (lane == 0) out[a] = pr + ba3[0];
}

extern "C" void kernel_launch(void* const* d_in, const int* in_sizes, int n_in,
                              void* d_out, int out_size, void* d_ws, size_t ws_size,
                              hipStream_t stream)
{
  const float* rij         = (const float*)d_in[0];
  const int*   species     = (const int*)  d_in[1];
  const int*   first_atom  = (const int*)  d_in[2];
  const int*   second_atom = (const int*)  d_in[3];
  const float* Wr1 = (const float*)d_in[4];
  const float* br1 = (const float*)d_in[5];
  const float* Wr2 = (const float*)d_in[6];
  const float* br2 = (const float*)d_in[7];
  const float* Ws1 = (const float*)d_in[8];
  const float* bs1 = (const float*)d_in[9];
  const float* Ws2 = (const float*)d_in[10];
  const float* bs2 = (const float*)d_in[11];
  const float* Wa1 = (const float*)d_in[12];
  const float* ba1 = (const float*)d_in[13];
  const float* Wa2 = (const float*)d_in[14];
  const float* ba2 = (const float*)d_in[15];
  const float* Wa3 = (const float*)d_in[16];
  const float* ba3 = (const float*)d_in[17];
  float* ws  = (float*)d_ws;
  float* out = (float*)d_out;

  k_pre<<<(NK * 12) / 256, 256, 0, stream>>>(Wr1, br1, Wr2, br2, Ws1, bs1, Ws2, bs2,
                                             Wa1, Wa2, ws);
  k_scatter<<<NEDGES / 256, 256, 0, stream>>>(rij, first_atom, second_atom, species, ws);
  k_acc<<<NATOMS / 2, 128, 0, stream>>>(ws);
  k_mlp<<<NATOMS / 4, 256, 0, stream>>>(ws, ba1, ba2, Wa3, ba3, out);
}

// Round 12
// 172.698 us; speedup vs baseline: 1.3576x; 1.3576x over previous
//
#include <hip/hip_runtime.h>
#include <math.h>

#define NATOMS 10000
#define NEDGES 320000
#define CAP    64             // fixed record capacity per (atom,species) bin
#define RC_F 5.0f
#define PI_F 3.14159265358979323846f

// radial table: T[k][0..47] = (R * fc)(d_k), d_k = k * RC/(NK-1), linear interp
#define NK   16384
#define TROW 48
#define HINV_F ((float)(NK - 1) / RC_F)

// ---- workspace layout (in floats) ----
#define WS_SEMB   0         // 12 floats
#define WS_CNT    16        // NATOMS int4 (species counts 0..2, .w unused)
#define WS_SD     440096    // NATOMS*3*CAP float4 records (30.7 MB), fixed-cap bins
#define WS_TAB    8200096   // NK*TROW floats (3 MB) radial table

// multinomial term tables (global component index 0..34)
__device__ __constant__ int   d_PWA[35] = {0, 0,0,1, 0,0,0,1,1,2, 0,0,0,0,1,1,1,2,2,3, 0,0,0,0,0,1,1,1,1,2,2,2,3,3,4};
__device__ __constant__ int   d_PWB[35] = {0, 0,1,0, 0,1,2,0,1,0, 0,1,2,3,0,1,2,0,1,0, 0,1,2,3,4,0,1,2,3,0,1,2,0,1,0};
__device__ __constant__ int   d_PWC[35] = {0, 1,0,0, 2,1,0,1,0,0, 3,2,1,0,2,1,0,1,0,0, 4,3,2,1,0,3,2,1,0,2,1,0,1,0,0};
__device__ __constant__ float d_NM[35]  = {1.f, 1.f,1.f,1.f, 1.f,2.f,1.f,2.f,2.f,1.f,
                                           1.f,3.f,3.f,1.f,3.f,6.f,3.f,3.f,3.f,1.f,
                                           1.f,4.f,6.f,4.f,1.f,4.f,12.f,12.f,4.f,6.f,12.f,6.f,4.f,4.f,1.f};
__device__ __constant__ int   d_LBLK[35]= {0, 1,1,1, 2,2,2,2,2,2, 3,3,3,3,3,3,3,3,3,3, 4,4,4,4,4,4,4,4,4,4,4,4,4,4,4};
__device__ __constant__ int   d_L6[6]   = {0,1,4,10,20,35};

__device__ __forceinline__ float siluf(float x) { return x / (1.0f + __expf(-x)); }

__device__ __forceinline__ float2 f2fma(float2 a, float2 b, float2 c) {
  return make_float2(fmaf(a.x, b.x, c.x), fmaf(a.y, b.y, c.y));
}

__device__ __forceinline__ float psel(float x, int p) {
  float x2 = x * x;
  float r = 1.0f;
  r = (p == 1) ? x : r;
  r = (p == 2) ? x2 : r;
  r = (p == 3) ? x2 * x : r;
  r = (p == 4) ? x2 * x2 : r;
  return r;
}

// ---------------- k_pre: zero counters + species embedding + radial table ----------------
// grid 768 x 256 = 196608 threads = NK*12 table items exactly; zeroing rides along.
__global__ __launch_bounds__(256) void k_pre(
    const float* __restrict__ Wr1, const float* __restrict__ br1,
    const float* __restrict__ Wr2, const float* __restrict__ br2,
    const float* __restrict__ Ws1, const float* __restrict__ bs1,
    const float* __restrict__ Ws2, const float* __restrict__ bs2,
    float* __restrict__ ws)
{
  int gt = blockIdx.x * 256 + threadIdx.x;

  // zero cnt (int4 per atom)
  if (gt < NATOMS) ((int4*)(ws + WS_CNT))[gt] = make_int4(0, 0, 0, 0);
  // species embedding
  if (gt < 12) {
    int t = gt >> 2, s = gt & 3;
    float acc = bs2[s];
    for (int j = 0; j < 16; j++) acc += tanhf(Ws1[t * 16 + j] + bs1[j]) * Ws2[j * 4 + s];
    ws[WS_SEMB + gt] = acc;
  }

  // radial table: item = (knot k, slice sl)
  int sl = gt % 12;
  int k  = gt / 12;           // 0..NK-1 exactly
  float dk = (float)k * (RC_F / (float)(NK - 1));
  float d = fmaxf(dk, 1e-6f);
  float invd = 1.0f / d;
  float theta = (PI_F / RC_F) * d;
  float s1 = sinf(theta), c1 = cosf(theta);
  float fc = (d < RC_F) ? 0.5f * (c1 + 1.0f) : 0.0f;
  float bes[8];
  {
    float sq = sqrtf(2.0f / RC_F) * invd;
    float twoc = 2.0f * c1;
    float sp = 0.0f, sc = s1;
    #pragma unroll
    for (int q = 0; q < 8; q++) {
      bes[q] = sq * sc;
      float sn = twoc * sc - sp;
      sp = sc; sc = sn;
    }
  }
  float h1[64];
  #pragma unroll
  for (int j4 = 0; j4 < 16; j4++) {
    float2 a01 = *(const float2*)&br1[j4 * 4];
    float2 a23 = *(const float2*)&br1[j4 * 4 + 2];
    #pragma unroll
    for (int q = 0; q < 8; q++) {
      float2 b2 = make_float2(bes[q], bes[q]);
      a01 = f2fma(b2, *(const float2*)&Wr1[q * 64 + j4 * 4],     a01);
      a23 = f2fma(b2, *(const float2*)&Wr1[q * 64 + j4 * 4 + 2], a23);
    }
    h1[j4 * 4 + 0] = siluf(a01.x);
    h1[j4 * 4 + 1] = siluf(a01.y);
    h1[j4 * 4 + 2] = siluf(a23.x);
    h1[j4 * 4 + 3] = siluf(a23.y);
  }
  int j0 = sl * 4;
  float2 a01 = *(const float2*)&br2[j0];
  float2 a23 = *(const float2*)&br2[j0 + 2];
  for (int q = 0; q < 64; q++) {
    float2 h2 = make_float2(h1[q], h1[q]);
    a01 = f2fma(h2, *(const float2*)&Wr2[q * 48 + j0],     a01);
    a23 = f2fma(h2, *(const float2*)&Wr2[q * 48 + j0 + 2], a23);
  }
  *(float4*)(ws + WS_TAB + (size_t)k * TROW + j0) =
      make_float4(siluf(a01.x) * fc, siluf(a01.y) * fc,
                  siluf(a23.x) * fc, siluf(a23.y) * fc);
}

// ---------------- k_scatter: direct allocation into fixed-capacity bins ----------------
__global__ __launch_bounds__(256) void k_scatter(
    const float* __restrict__ rij,
    const int* __restrict__ first_atom, const int* __restrict__ second_atom,
    const int* __restrict__ species, float* __restrict__ ws)
{
  int e = blockIdx.x * 256 + threadIdx.x;   // grid exact: NEDGES = 1250*256
  int* cnt = (int*)(ws + WS_CNT);
  int a = first_atom[e];
  int t = species[second_atom[e]];
  int pos = atomicAdd(&cnt[a * 4 + t], 1);
  float x = rij[e * 3 + 0], y = rij[e * 3 + 1], z = rij[e * 3 + 2];
  float d = sqrtf(x * x + y * y + z * z + 1e-12f);
  float invd = 1.0f / d;
  if (pos < CAP)
    ((float4*)(ws + WS_SD))[(size_t)a * (3 * CAP) + t * CAP + pos] =
        make_float4(x * invd, y * invd, z * invd, d);
}

// ---------------- k_atom: one wave per atom; merged virtual stream (2 rounds/atom) ----------------
// Round-7 staging pipeline (coalesced 16-record load + shfl distribution) kept
// verbatim; the three per-species padded round loops are fused into one stream
// g in [0, c0+c1+c2) with per-lane (T,loc) mapping and CORE split at run
// boundaries. Accumulation order per species unchanged -> bit-identical.
__global__ __launch_bounds__(128) void k_atom(
    const float* __restrict__ ws,
    const float* __restrict__ Wa1, const float* __restrict__ ba1,
    const float* __restrict__ Wa2, const float* __restrict__ ba2,
    const float* __restrict__ Wa3, const float* __restrict__ ba3,
    float* __restrict__ out)
{
  __shared__ __align__(16) float sScr[2][1120];
  int tid = threadIdx.x;
  int lane = tid & 63, wv = tid >> 6;
  int a = blockIdx.x * 2 + wv;          // NATOMS = 5000*2 exact
  float* sStage = &sScr[wv][0];         // 16 records x 52 floats (during runs)
  float* sG     = &sScr[wv][0];         // 24 x 36 (after runs; overlays sStage)
  float* sFeat  = &sScr[wv][864];       // 192
  float* sH     = &sScr[wv][1056];      // 64

  const float4* sd4 = (const float4*)(ws + WS_SD);
  const float* tab = ws + WS_TAB;

  const int c = lane;
  bool isc = (c < 35);
  int pa = 0, pb = 0, pcw = 0, lb = 0;
  if (isc) { pa = d_PWA[c]; pb = d_PWB[c]; pcw = d_PWC[c]; lb = d_LBLK[c]; }
  int rdir = lane - 35;
  bool isd = (rdir >= 0) && (rdir < 8);
  int rl = lane >> 4, fl = lane & 15;
  int s = lane & 3;
  float se0 = ws[WS_SEMB + s], se1 = ws[WS_SEMB + 4 + s], se2 = ws[WS_SEMB + 8 + s];

  int4 cv = ((const int4*)(ws + WS_CNT))[a];
  int c0n = cv.x > CAP ? CAP : cv.x;
  int c1n = cv.y > CAP ? CAP : cv.y;
  int c2n = cv.z > CAP ? CAP : cv.z;
  int b1 = c0n, b2 = c0n + c1n, tot = b2 + c2n;

  float2 g2[3][4];
  #pragma unroll
  for (int t2 = 0; t2 < 3; t2++)
    #pragma unroll
    for (int r = 0; r < 4; r++) g2[t2][r] = make_float2(0.f, 0.f);
  float g0[3] = {0.0f, 0.0f, 0.0f};

#define CORE(T) {                                                             \
    const float* rb = sStage + j * 52;                                        \
    if (isc) {                                                                \
      float4 rh = *(const float4*)(rb + 48);                                  \
      float comp = psel(rh.x, pa) * psel(rh.y, pb) * psel(rh.z, pcw);         \
      float2 c2v = make_float2(comp, comp);                                   \
      const float2* r2 = (const float2*)(rb + 8 + 8 * lb);                    \
      g2[T][0] = f2fma(c2v, r2[0], g2[T][0]);                                 \
      g2[T][1] = f2fma(c2v, r2[1], g2[T][1]);                                 \
      g2[T][2] = f2fma(c2v, r2[2], g2[T][2]);                                 \
      g2[T][3] = f2fma(c2v, r2[3], g2[T][3]);                                 \
    } else if (isd) {                                                         \
      g0[T] += rb[rdir];                                                      \
    }                                                                         \
  }

  {
    const float4* rbase = sd4 + (size_t)a * (3 * CAP);
    for (int cb = 0; cb < tot; cb += 16) {
      int m = tot - cb; if (m > 16) m = 16;
      int g = cb + ((lane < m) ? lane : (m - 1));
      int T = (g >= b1) + (g >= b2);
      int loc = g - ((T == 0) ? 0 : ((T == 1) ? b1 : b2));
      float4 ed = rbase[T * CAP + loc];
      float fi = ed.w * HINV_F;
      int ii = (int)fi;
      ii = (ii > NK - 2) ? (NK - 2) : ii;
      float w = fi - (float)ii;
      int rowb = ii * TROW;
      int R = (m + 3) >> 2;
      for (int r = 0; r < R; r++) {
        int sl = r * 4 + rl;
        float w_s = __shfl(w, sl, 64);
        int   rb_ = __shfl(rowb, sl, 64);
        float sx = __shfl(ed.x, sl, 64), sy = __shfl(ed.y, sl, 64);
        float sz = __shfl(ed.z, sl, 64);
        if (fl < 12) {
          const float* tp = tab + rb_ + fl * 4;
          float4 t0 = *(const float4*)(tp);
          float4 t1 = *(const float4*)(tp + TROW);
          float4 v;
          v.x = fmaf(w_s, t1.x - t0.x, t0.x);
          v.y = fmaf(w_s, t1.y - t0.y, t0.y);
          v.z = fmaf(w_s, t1.z - t0.z, t0.z);
          v.w = fmaf(w_s, t1.w - t0.w, t0.w);
          *(float4*)(sStage + sl * 52 + fl * 4) = v;
        } else if (fl == 12) {
          *(float4*)(sStage + sl * 52 + 48) = make_float4(sx, sy, sz, 0.0f);
        }
      }
      int jb1 = b1 - cb; jb1 = jb1 < 0 ? 0 : (jb1 > m ? m : jb1);
      int jb2 = b2 - cb; jb2 = jb2 < 0 ? 0 : (jb2 > m ? m : jb2);
      int j = 0;
      for (; j < jb1; j++) CORE(0)
      for (; j < jb2; j++) CORE(1)
      for (; j < m;   j++) CORE(2)
    }
  }
#undef CORE

  if (isc) {
    #pragma unroll
    for (int t2 = 0; t2 < 3; t2++)
      #pragma unroll
      for (int r = 0; r < 8; r++) {
        float gval = (r & 1) ? g2[t2][r >> 1].y : g2[t2][r >> 1].x;
        sG[(t2 * 8 + r) * 36 + c] = gval;
      }
  } else if (isd) {
    #pragma unroll
    for (int t2 = 0; t2 < 3; t2++) sG[(t2 * 8 + rdir) * 36 + 35] = g0[t2];
  }

  float fout[3];
  #pragma unroll
  for (int u = 0; u < 3; u++) {
    int f = lane + 64 * u;
    int blk = f >> 5, rr = (f >> 2) & 7;
    float acc;
    if (blk == 0) {
      acc = se0 * sG[(0 + rr) * 36 + 35] + se1 * sG[(8 + rr) * 36 + 35] + se2 * sG[(16 + rr) * 36 + 35];
    } else {
      int cc0 = d_L6[blk - 1], cc1 = d_L6[blk];
      acc = 0.0f;
      for (int cc = cc0; cc < cc1; cc++) {
        float A = se0 * sG[(0 + rr) * 36 + cc] + se1 * sG[(8 + rr) * 36 + cc] + se2 * sG[(16 + rr) * 36 + cc];
        acc += d_NM[cc] * A * A;
      }
    }
    fout[u] = acc;
  }
  #pragma unroll
  for (int u = 0; u < 3; u++) sFeat[lane + 64 * u] = fout[u];

  {
    float a0_ = 0.f, a1_ = 0.f, a2_ = 0.f, a3_ = 0.f;
    for (int k4 = 0; k4 < 48; k4++) {
      float4 f4 = *(const float4*)(sFeat + k4 * 4);
      const float* wp = Wa1 + (k4 * 4) * 64 + lane;
      a0_ += f4.x * wp[0];
      a1_ += f4.y * wp[64];
      a2_ += f4.z * wp[128];
      a3_ += f4.w * wp[192];
    }
    sH[lane] = siluf(a0_ + a1_ + a2_ + a3_ + ba1[lane]);
  }

  {
    float a0_ = 0.f, a1_ = 0.f, a2_ = 0.f, a3_ = 0.f;
    for (int k4 = 0; k4 < 16; k4++) {
      float4 h4 = *(const float4*)(sH + k4 * 4);
      const float* wp = Wa2 + (k4 * 4) * 64 + lane;
      a0_ += h4.x * wp[0];
      a1_ += h4.y * wp[64];
      a2_ += h4.z * wp[128];
      a3_ += h4.w * wp[192];
    }
    float h2 = siluf(a0_ + a1_ + a2_ + a3_ + ba2[lane]);
    float pr = h2 * Wa3[lane];
    #pragma unroll
    for (int off = 32; off > 0; off >>= 1) pr += __shfl_down(pr, off, 64);
    if (lane == 0) out[a] = pr + ba3[0];
  }
}

extern "C" void kernel_launch(void* const* d_in, const int* in_sizes, int n_in,
                              void* d_out, int out_size, void* d_ws, size_t ws_size,
                              hipStream_t stream)
{
  const float* rij         = (const float*)d_in[0];
  const int*   species     = (const int*)  d_in[1];
  const int*   first_atom  = (const int*)  d_in[2];
  const int*   second_atom = (const int*)  d_in[3];
  const float* Wr1 = (const float*)d_in[4];
  const float* br1 = (const float*)d_in[5];
  const float* Wr2 = (const float*)d_in[6];
  const float* br2 = (const float*)d_in[7];
  const float* Ws1 = (const float*)d_in[8];
  const float* bs1 = (const float*)d_in[9];
  const float* Ws2 = (const float*)d_in[10];
  const float* bs2 = (const float*)d_in[11];
  const float* Wa1 = (const float*)d_in[12];
  const float* ba1 = (const float*)d_in[13];
  const float* Wa2 = (const float*)d_in[14];
  const float* ba2 = (const float*)d_in[15];
  const float* Wa3 = (const float*)d_in[16];
  const float* ba3 = (const float*)d_in[17];
  float* ws  = (float*)d_ws;
  float* out = (float*)d_out;

  k_pre<<<(NK * 12) / 256, 256, 0, stream>>>(Wr1, br1, Wr2, br2, Ws1, bs1, Ws2, bs2, ws);
  k_scatter<<<NEDGES / 256, 256, 0, stream>>>(rij, first_atom, second_atom, species, ws);
  k_atom<<<NATOMS / 2, 128, 0, stream>>>(ws, Wa1, ba1, Wa2, ba2, Wa3, ba3, out);
}